// Round 6
// baseline (609.278 us; speedup 1.0000x reference)
//
#include <hip/hip_runtime.h>
#include <hip/hip_fp16.h>
#include <cstdint>
#include <cstddef>

constexpr int NN  = 100000;
constexpr int EE  = 1600000;
constexpr int HID = 128;
constexpr int BUK = 256;                      // nodes per bucket (local id fits 8 bits)
constexpr int NBUK = (NN + BUK - 1) / BUK;    // 391 buckets
constexpr int BLKE = 2048;                    // edges per block in bucket passes
constexpr int NBE  = (EE + BLKE - 1) / BLKE;  // 782 edge blocks
constexpr int MH   = NBUK * NBE;              // 305762 flattened hist entries
constexpr int NSC  = (MH + 1023) / 1024;      // 299 scan chunks (<=512 for scan_top)

typedef float f32x4_t __attribute__((ext_vector_type(4)));
typedef short bf16x8_t __attribute__((ext_vector_type(8)));

static __device__ __forceinline__ short f2bf(float f) {
    union { float f; unsigned u; } x; x.f = f;
    unsigned r = x.u + 0x7FFF + ((x.u >> 16) & 1);   // RN-even
    return (short)(r >> 16);
}
static __device__ __forceinline__ float bf2f(short b) {
    union { unsigned u; float f; } x; x.u = ((unsigned)(unsigned short)b) << 16;
    return x.f;
}

// ---------------------------------------------------------------- pass 1: per-block bucket histograms, both sides (LDS atomics only)
// R1 post-mortem: global atomicAdd per edge = 71 us, VALUBusy 0.6%. LDS only.
__global__ __launch_bounds__(256) void bh_both_k(const int* __restrict__ src, const int* __restrict__ dst,
                                                 int* __restrict__ bh_d, int* __restrict__ bh_s) {
    __shared__ int hd[NBUK], hs[NBUK];
    int blk = blockIdx.x, t = threadIdx.x;
    for (int i = t; i < NBUK; i += 256) { hd[i] = 0; hs[i] = 0; }
    __syncthreads();
    int e0 = blk * BLKE, e1 = min(e0 + BLKE, EE);
    for (int e = e0 + t; e < e1; e += 256) {
        atomicAdd(&hd[dst[e] >> 8], 1);
        atomicAdd(&hs[src[e] >> 8], 1);
    }
    __syncthreads();
    for (int i = t; i < NBUK; i += 256) {
        bh_d[i * NBE + blk] = hd[i];
        bh_s[i * NBE + blk] = hs[i];
    }
}

// ---------------------------------------------------------------- 3-level exclusive scan (length n)
__global__ __launch_bounds__(256) void scan_sum_k(const int* __restrict__ in, int* __restrict__ bsum, int n) {
    __shared__ int sc[256];
    int b = blockIdx.x, t = threadIdx.x;
    int base = b * 1024 + t * 4;
    int s = 0;
#pragma unroll
    for (int j = 0; j < 4; j++) { int idx = base + j; s += (idx < n) ? in[idx] : 0; }
    sc[t] = s; __syncthreads();
    for (int off = 128; off > 0; off >>= 1) {
        if (t < off) sc[t] += sc[t + off];
        __syncthreads();
    }
    if (t == 0) bsum[b] = sc[0];
}

__global__ __launch_bounds__(512) void scan_top_k(const int* __restrict__ bsum, int* __restrict__ boff, int nb) {
    __shared__ int sc[512];
    int t = threadIdx.x;
    int v = (t < nb) ? bsum[t] : 0;
    sc[t] = v; __syncthreads();
    for (int off = 1; off < 512; off <<= 1) {
        int u = (t >= off) ? sc[t - off] : 0;
        __syncthreads();
        sc[t] += u;
        __syncthreads();
    }
    if (t < nb) boff[t] = sc[t] - v;
}

__global__ __launch_bounds__(256) void scan_chunk_k(const int* __restrict__ in, const int* __restrict__ boff,
                                                    int* __restrict__ out, int n) {
    __shared__ int sc[256];
    int b = blockIdx.x, t = threadIdx.x;
    int base = b * 1024 + t * 4;
    int c[4];
#pragma unroll
    for (int j = 0; j < 4; j++) { int idx = base + j; c[j] = (idx < n) ? in[idx] : 0; }
    int s = c[0] + c[1] + c[2] + c[3];
    sc[t] = s; __syncthreads();
    for (int off = 1; off < 256; off <<= 1) {
        int v = (t >= off) ? sc[t - off] : 0;
        __syncthreads();
        sc[t] += v;
        __syncthreads();
    }
    int excl = sc[t] - s + boff[b];
#pragma unroll
    for (int j = 0; j < 4; j++) {
        int idx = base + j;
        if (idx < n) out[idx] = excl;
        excl += c[j];
    }
}

// ---------------------------------------------------------------- pass 2: scatter into bucket order (LDS cursors)
// dst side: packed 25-bit payload (d_local<<17 | src); src side: low byte only
__global__ __launch_bounds__(256) void scatter_both_k(const int* __restrict__ src, const int* __restrict__ dst,
                                                      const int* __restrict__ off_d, const int* __restrict__ off_s,
                                                      unsigned* __restrict__ pairs, unsigned char* __restrict__ sbyte) {
    __shared__ int cd[NBUK], cs[NBUK];
    int blk = blockIdx.x, t = threadIdx.x;
    for (int i = t; i < NBUK; i += 256) {
        cd[i] = off_d[i * NBE + blk];
        cs[i] = off_s[i * NBE + blk];
    }
    __syncthreads();
    int e0 = blk * BLKE, e1 = min(e0 + BLKE, EE);
    for (int e = e0 + t; e < e1; e += 256) {
        int d = dst[e], s = src[e];
        int pd = atomicAdd(&cd[d >> 8], 1);
        pairs[pd] = ((unsigned)(d & 255) << 17) | (unsigned)s;
        int ps = atomicAdd(&cs[s >> 8], 1);
        sbyte[ps] = (unsigned char)(s & 255);
    }
}

// ---------------------------------------------------------------- per-bucket work, fused:
// blocks [0, NBUK):     in-deg hist -> inorm, rowptr, col  (from pairs)
// blocks [NBUK, 2*NBUK): out-deg hist -> onorm             (from sbyte)
__global__ __launch_bounds__(512) void bucket_csr_ocnt_k(
    const unsigned* __restrict__ pairs, const int* __restrict__ off_d,
    const unsigned char* __restrict__ sbyte, const int* __restrict__ off_s,
    int* __restrict__ rowptr, int* __restrict__ col,
    float* __restrict__ inorm, float* __restrict__ onorm) {
    __shared__ int hist[BUK];
    __shared__ int excl[BUK];
    __shared__ int psum[BUK];
    int t = threadIdx.x;

    if (blockIdx.x >= NBUK) {            // -------- out-degree counting
        int b = blockIdx.x - NBUK;
        int base = off_s[b * NBE];
        int endv = (b == NBUK - 1) ? EE : off_s[(b + 1) * NBE];
        if (t < BUK) hist[t] = 0;
        __syncthreads();
        for (int i = base + t; i < endv; i += 512) atomicAdd(&hist[sbyte[i]], 1);
        __syncthreads();
        if (t < BUK) {
            int node = b * BUK + t;
            if (node < NN) {
                int c = hist[t]; if (c < 1) c = 1;
                onorm[node] = rsqrtf((float)c);
            }
        }
        return;
    }

    // ------------------------------------------- CSR build
    int b = blockIdx.x;
    int base = off_d[b * NBE];
    int endv = (b == NBUK - 1) ? EE : off_d[(b + 1) * NBE];
    if (t < BUK) hist[t] = 0;
    __syncthreads();
    for (int i = base + t; i < endv; i += 512) atomicAdd(&hist[pairs[i] >> 17], 1);
    __syncthreads();
    int ps = 0;
    if (t < BUK) { ps = hist[t]; psum[t] = ps; }
    __syncthreads();
    for (int off = 1; off < BUK; off <<= 1) {
        int u = 0;
        if (t < BUK && t >= off) u = psum[t - off];
        __syncthreads();
        if (t < BUK) psum[t] += u;
        __syncthreads();
    }
    if (t < BUK) {
        int pex = psum[t] - ps;
        excl[t] = pex;
        int node = b * BUK + t;
        if (node < NN) {
            rowptr[node] = base + pex;
            int c = ps; if (c < 1) c = 1;
            inorm[node] = rsqrtf((float)c);
        }
    }
    if (b == NBUK - 1 && t == 0) rowptr[NN] = EE;
    __syncthreads();
    for (int i = base + t; i < endv; i += 512) {
        unsigned p = pairs[i];
        int pos = base + atomicAdd(&excl[p >> 17], 1);
        col[pos] = (int)(p & 0x1FFFFu);
    }
}

// ---------------------------------------------------------------- W12 = W1 @ W2 ; b12 = b1 @ W2 + b2 (merged)
__global__ __launch_bounds__(256) void w12_k(const float* __restrict__ W1, const float* __restrict__ W2,
                                             const float* __restrict__ b1, const float* __restrict__ b2,
                                             float* __restrict__ W12, float* __restrict__ b12) {
    if (blockIdx.x == 64) {
        int j = threadIdx.x;
        if (j < 128) {
            float acc = b2[j];
            for (int k = 0; k < 128; k++) acc = fmaf(b1[k], W2[k * 128 + j], acc);
            b12[j] = acc;
        }
        return;
    }
    int idx = blockIdx.x * 256 + threadIdx.x;   // 0..16383
    int i = idx >> 7, j = idx & 127;
    float a0 = 0.f, a1 = 0.f, a2 = 0.f, a3 = 0.f;
    for (int k = 0; k < 128; k += 4) {
        a0 = fmaf(W1[i * 128 + k],     W2[(k)     * 128 + j], a0);
        a1 = fmaf(W1[i * 128 + k + 1], W2[(k + 1) * 128 + j], a1);
        a2 = fmaf(W1[i * 128 + k + 2], W2[(k + 2) * 128 + j], a2);
        a3 = fmaf(W1[i * 128 + k + 3], W2[(k + 3) * 128 + j], a3);
    }
    W12[idx] = (a0 + a1) + (a2 + a3);
}

// ---------------------------------------------------------------- FUSED gather + GraphConv (R6)
// Per 16-node tile: quarter-wave q of wave w gathers node tile*16+w*4+q
// (4 edges in flight, agg_k's proven loop), stages the fp32 row in LDS
// (same precision path as the old h0 round-trip, minus 100MB/layer of HBM),
// then MFMAs vs REGISTER-resident split-bf16 weights: wave w owns global
// cols kq*32 + w*8 + {0..7} (2 chunks x 4 regs), so each thread stores one
// contiguous 8-col run (fp16 16B / fp32 32B). NN = 6250*16 exactly -> no
// ragged tile. Weights as A-operand (D col = node), per R5.
template <bool LAST>   // LAST: fp32 out (classifier input), no onorm
__global__ __launch_bounds__(256) void agg_conv_k(
    const float4* __restrict__ h16, const int* __restrict__ rowptr,
    const int* __restrict__ col, const float* __restrict__ inorm,
    const float* __restrict__ onorm, const float* __restrict__ W,
    const float* __restrict__ bias, void* __restrict__ outp, int ntiles) {

    __shared__ float Ast[16 * 132];   // 16 nodes x 128 feats, stride 132 (16B-aligned rows)
    const int t = threadIdx.x;
    const int wave = t >> 6, lane = t & 63;
    const int q = lane >> 4, l16 = lane & 15;

    // ---- weight A-fragments in registers (loop-invariant, 64 VGPR)
    // A[row=wc][k]: lane holds wc = lane&15, k = (lane>>4)*8 + j (+kb*32).
    // chunk (wave,ntc) row wc <-> global col g = (wc>>2)*32 + wave*8 + ntc*4 + (wc&3)
    bf16x8_t Wh[2][4], Wl[2][4];
    {
        const int gb = ((l16 >> 2) << 5) + wave * 8 + (l16 & 3);
#pragma unroll
        for (int ntc = 0; ntc < 2; ntc++) {
#pragma unroll
            for (int kb = 0; kb < 4; kb++) {
#pragma unroll
                for (int j = 0; j < 8; j++) {
                    float wv = W[(kb * 32 + q * 8 + j) * 128 + gb + ntc * 4];
                    short hi = f2bf(wv);
                    Wh[ntc][kb][j] = hi;
                    Wl[ntc][kb][j] = f2bf(wv - bf2f(hi));
                }
            }
        }
    }
    const int cbase = q * 32 + wave * 8;    // thread's first output col
    float bstat[8];
#pragma unroll
    for (int i = 0; i < 8; i++) bstat[i] = bias[cbase + i];

    union HU { float4 f4; __half2 h2[4]; };

    for (int tile = blockIdx.x; tile < ntiles; tile += gridDim.x) {
        // ---------------- gather phase: quarter q owns one node
        {
            const int node = tile * 16 + wave * 4 + q;
            int i = rowptr[node];
            const int end = rowptr[node + 1];
            float acc[8];
#pragma unroll
            for (int j = 0; j < 8; j++) acc[j] = 0.f;
            for (; i + 3 < end; i += 4) {
                int s0 = col[i], s1 = col[i + 1], s2 = col[i + 2], s3 = col[i + 3];
                HU u0, u1, u2, u3;
                u0.f4 = h16[(size_t)s0 * 16 + l16];
                u1.f4 = h16[(size_t)s1 * 16 + l16];
                u2.f4 = h16[(size_t)s2 * 16 + l16];
                u3.f4 = h16[(size_t)s3 * 16 + l16];
#pragma unroll
                for (int p = 0; p < 4; p++) {
                    float2 a = __half22float2(u0.h2[p]);
                    float2 b = __half22float2(u1.h2[p]);
                    float2 c = __half22float2(u2.h2[p]);
                    float2 d = __half22float2(u3.h2[p]);
                    acc[2 * p]     += (a.x + b.x) + (c.x + d.x);
                    acc[2 * p + 1] += (a.y + b.y) + (c.y + d.y);
                }
            }
            for (; i < end; ++i) {
                HU u; u.f4 = h16[(size_t)col[i] * 16 + l16];
#pragma unroll
                for (int p = 0; p < 4; p++) {
                    float2 a = __half22float2(u.h2[p]);
                    acc[2 * p]     += a.x;
                    acc[2 * p + 1] += a.y;
                }
            }
            float* ap = &Ast[(wave * 4 + q) * 132 + l16 * 8];
            *(float4*)ap       = make_float4(acc[0], acc[1], acc[2], acc[3]);
            *(float4*)(ap + 4) = make_float4(acc[4], acc[5], acc[6], acc[7]);
        }
        __syncthreads();

        // ---------------- conv phase: B-fragment = node m=l16, k-quarter q
        const int row = tile * 16 + l16;
        const float s = inorm[row];
        bf16x8_t Bh_[4], Bl_[4];
#pragma unroll
        for (int kb = 0; kb < 4; kb++) {
            const float* rp = &Ast[l16 * 132 + kb * 32 + q * 8];
            float4 p0 = *(const float4*)rp;
            float4 p1 = *(const float4*)(rp + 4);
            float av[8] = {p0.x, p0.y, p0.z, p0.w, p1.x, p1.y, p1.z, p1.w};
#pragma unroll
            for (int j = 0; j < 8; j++) {
                float v = av[j] * s;
                short hi = f2bf(v);
                Bh_[kb][j] = hi;
                Bl_[kb][j] = f2bf(v - bf2f(hi));
            }
        }
        float osc = 1.f;
        if constexpr (!LAST) osc = onorm[row];
        float ov[8] __attribute__((aligned(16)));
#pragma unroll
        for (int ntc = 0; ntc < 2; ntc++) {
            f32x4_t acc = {0.f, 0.f, 0.f, 0.f};
#pragma unroll
            for (int kb = 0; kb < 4; kb++) {
                acc = __builtin_amdgcn_mfma_f32_16x16x32_bf16(Wh[ntc][kb], Bh_[kb], acc, 0, 0, 0);
                acc = __builtin_amdgcn_mfma_f32_16x16x32_bf16(Wh[ntc][kb], Bl_[kb], acc, 0, 0, 0);
                acc = __builtin_amdgcn_mfma_f32_16x16x32_bf16(Wl[ntc][kb], Bh_[kb], acc, 0, 0, 0);
            }
#pragma unroll
            for (int r = 0; r < 4; r++) {
                float v = fmaxf(acc[r] + bstat[ntc * 4 + r], 0.f);   // ReLU (all 3 layers)
                ov[ntc * 4 + r] = v * osc;
            }
        }
        if constexpr (LAST) {
            float* p = (float*)outp + (size_t)row * 128 + cbase;
            *(float4*)p       = *(const float4*)&ov[0];
            *(float4*)(p + 4) = *(const float4*)&ov[4];
        } else {
            union { __half h[8]; float4 f4; } U;
#pragma unroll
            for (int j = 0; j < 8; j++) U.h[j] = __float2half_rn(ov[j]);
            *(float4*)((__half*)outp + (size_t)row * 128 + cbase) = U.f4;
        }
        __syncthreads();   // Ast reused next tile
    }
}

// ---------------------------------------------------------------- split-bf16 MFMA GEMM, operand-swapped epilogue (R5-proven)
template <int NT, bool RELU, bool INSCALE, bool OUTSCALE, bool OUTHALF>
__global__ __launch_bounds__(256) void mfma_gemm_k(
    const float* __restrict__ in, const float* __restrict__ inscale,
    const float* __restrict__ W, const float* __restrict__ bias,
    void* __restrict__ outp, const float* __restrict__ outscale,
    int nrows, int ncols, int ntiles) {

    __shared__ short Bh[NT * 2048];   // [ntc][kblk(4)][lane(64)][j(8)]
    __shared__ short Bl[NT * 2048];

    const int t = threadIdx.x;

    if constexpr (NT == 8) {
        for (int j = 0; j < 16; j++) {
            int fi = (j * 256 + t) * 4;
            int k = fi >> 7, n0 = fi & 127;
            float4 wv = *(const float4*)(W + fi);
            float wa[4] = {wv.x, wv.y, wv.z, wv.w};
#pragma unroll
            for (int cc = 0; cc < 4; cc++) {
                int g = n0 + cc;
                int q2 = g >> 2;
                int ntc = q2 & 7;                       // % NT (NT=8)
                int c = ((q2 >> 3) << 2) | (g & 3);     // (q2/NT)*4 + (g&3)
                int kblk = k >> 5, ksub = k & 31;
                int lane_ = ((ksub >> 3) << 4) | c;
                int sidx = ((ntc * 4 + kblk) * 64 + lane_) * 8 + (ksub & 7);
                short hi = f2bf(wa[cc]);
                Bh[sidx] = hi; Bl[sidx] = f2bf(wa[cc] - bf2f(hi));
            }
        }
    } else {  // classifier: 40 real cols, pad to NT*16=48
        for (int idx = t; idx < 128 * 64; idx += 256) {
            int k = idx >> 6, g = idx & 63;
            if (g < NT * 16) {
                float w = (g < 40) ? W[k * 40 + g] : 0.f;
                int q2 = g >> 2;
                int ntc = q2 % NT;
                int c = (q2 / NT) * 4 + (g & 3);
                int kblk = k >> 5, ksub = k & 31;
                int lane_ = ((ksub >> 3) << 4) | c;
                int sidx = ((ntc * 4 + kblk) * 64 + lane_) * 8 + (ksub & 7);
                short hi = f2bf(w);
                Bh[sidx] = hi; Bl[sidx] = f2bf(w - bf2f(hi));
            }
        }
    }
    __syncthreads();   // LDS read-only below

    const int wave = t >> 6;
    const int lane = t & 63;
    const int m    = lane & 15;     // node within tile
    const int kq   = lane >> 4;
    const int cbase = kq * 4 * NT;  // this thread's first output col

    float bstat[4 * NT];
#pragma unroll
    for (int i = 0; i < 4 * NT; i++) {
        int g = cbase + i;
        bstat[i] = (g < ncols) ? bias[g] : 0.f;
    }

    const int wstride = gridDim.x * 4;
    for (int tile = blockIdx.x * 4 + wave; tile < ntiles; tile += wstride) {
        int row = tile * 16 + m;
        bool rv = row < nrows;

        bf16x8_t Ah[4], Al[4];
        float s = 1.f;
        if (INSCALE && rv) s = inscale[row];
#pragma unroll
        for (int kb = 0; kb < 4; kb++) {
            const float* ap = in + (size_t)row * 128 + kb * 32 + kq * 8;
            float4 p0, p1;
            if (rv) { p0 = *(const float4*)ap; p1 = *(const float4*)(ap + 4); }
            else    { p0 = make_float4(0,0,0,0); p1 = make_float4(0,0,0,0); }
            float av[8] = {p0.x, p0.y, p0.z, p0.w, p1.x, p1.y, p1.z, p1.w};
#pragma unroll
            for (int j = 0; j < 8; j++) {
                float v = INSCALE ? av[j] * s : av[j];
                short hi = f2bf(v);
                Ah[kb][j] = hi;
                Al[kb][j] = f2bf(v - bf2f(hi));
            }
        }

        float osc = 1.f;
        if (OUTSCALE && rv) osc = outscale[row];

        float ov[4 * NT] __attribute__((aligned(16)));
#pragma unroll
        for (int nt = 0; nt < NT; nt++) {
            f32x4_t acc = {0.f, 0.f, 0.f, 0.f};
#pragma unroll
            for (int kb = 0; kb < 4; kb++) {
                const bf16x8_t bh = *(const bf16x8_t*)&Bh[((nt * 4 + kb) * 64 + lane) * 8];
                const bf16x8_t bl = *(const bf16x8_t*)&Bl[((nt * 4 + kb) * 64 + lane) * 8];
                acc = __builtin_amdgcn_mfma_f32_16x16x32_bf16(bh, Ah[kb], acc, 0, 0, 0);
                acc = __builtin_amdgcn_mfma_f32_16x16x32_bf16(bh, Al[kb], acc, 0, 0, 0);
                acc = __builtin_amdgcn_mfma_f32_16x16x32_bf16(bl, Ah[kb], acc, 0, 0, 0);
            }
#pragma unroll
            for (int r = 0; r < 4; r++) {
                float v = acc[r] + bstat[nt * 4 + r];
                if (RELU) v = fmaxf(v, 0.f);
                ov[nt * 4 + r] = v * osc;
            }
        }

        if (rv) {
            if constexpr (OUTHALF) {
                union { __half h[4 * NT]; float4 f4[NT]; } U;
#pragma unroll
                for (int i = 0; i < 4 * NT; i++) U.h[i] = __float2half_rn(ov[i]);
                float4* p = (float4*)((__half*)outp + (size_t)row * ncols + cbase);
#pragma unroll
                for (int j = 0; j < NT; j += 2) p[j >> 1] = U.f4[j >> 1];   // NT=8: 4x16B
            } else if constexpr (NT == 8) {
                float4* p = (float4*)((float*)outp + (size_t)row * 128 + cbase);
#pragma unroll
                for (int j = 0; j < 8; j++) p[j] = ((const float4*)ov)[j];  // 8x16B
            } else {  // classifier fp32, ncols=40: cols cbase..cbase+11, skip >=40
                float* p = (float*)outp + (size_t)row * 40 + cbase;
#pragma unroll
                for (int j = 0; j < 3; j++) {
                    if (cbase + j * 4 < 40) *(float4*)(p + j * 4) = ((const float4*)ov)[j];
                }
            }
        }
    }
}

// ---------------------------------------------------------------- launch
extern "C" void kernel_launch(void* const* d_in, const int* in_sizes, int n_in,
                              void* d_out, int out_size, void* d_ws, size_t ws_size,
                              hipStream_t stream) {
    const float* x   = (const float*)d_in[0];
    const int*   src = (const int*)d_in[1];
    const int*   dst = (const int*)d_in[2];
    const float* W1  = (const float*)d_in[3];
    const float* b1  = (const float*)d_in[4];
    const float* W2  = (const float*)d_in[5];
    const float* b2  = (const float*)d_in[6];
    const float* Wg  = (const float*)d_in[7];   // [3][128][128]
    const float* bg  = (const float*)d_in[8];   // [3][128]
    const float* Wc  = (const float*)d_in[9];   // [128][40]
    const float* bc  = (const float*)d_in[10];  // [40]
    float* out = (float*)d_out;

    char* ws = (char*)d_ws;
    size_t off = 0;
    auto alloc = [&](size_t bytes) -> void* {
        void* p = ws + off;
        off += (bytes + 255) & ~(size_t)255;
        return p;
    };
    float*  h1     = (float*)alloc((size_t)NN * HID * 4);    // classifier input (fp32)
    __half* h16a   = (__half*)alloc((size_t)NN * HID * 2);   // fp16 ping
    __half* h16b   = (__half*)alloc((size_t)NN * HID * 2);   // fp16 pong
    float*  W12    = (float*)alloc(128 * 128 * 4);
    float*  b12    = (float*)alloc(128 * 4);
    float*  onorm  = (float*)alloc((size_t)NN * 4);
    float*  inorm  = (float*)alloc((size_t)NN * 4);
    int*    rowptr = (int*)alloc((size_t)(NN + 1) * 4);
    int*    col    = (int*)alloc((size_t)EE * 4);
    int*    bh_d   = (int*)alloc((size_t)MH * 4);
    int*    bh_s   = (int*)alloc((size_t)MH * 4);
    int*    off_d  = (int*)alloc((size_t)MH * 4);
    int*    off_s  = (int*)alloc((size_t)MH * 4);
    int*    bsum   = (int*)alloc((size_t)NSC * 4);
    int*    boff   = (int*)alloc((size_t)NSC * 4);
    // sort payloads alias h1 (consumed by bucket_csr_ocnt_k; h1 written only
    // by the LAST fused layer, long after)
    unsigned*      pairs = (unsigned*)h1;                          // 6.4 MB
    unsigned char* sbyte = (unsigned char*)h1 + (size_t)EE * 4;    // 1.6 MB

    // ---- CSR build (no global atomics)
    bh_both_k<<<NBE, 256, 0, stream>>>(src, dst, bh_d, bh_s);
    scan_sum_k<<<NSC, 256, 0, stream>>>(bh_d, bsum, MH);
    scan_top_k<<<1, 512, 0, stream>>>(bsum, boff, NSC);
    scan_chunk_k<<<NSC, 256, 0, stream>>>(bh_d, boff, off_d, MH);
    scan_sum_k<<<NSC, 256, 0, stream>>>(bh_s, bsum, MH);
    scan_top_k<<<1, 512, 0, stream>>>(bsum, boff, NSC);
    scan_chunk_k<<<NSC, 256, 0, stream>>>(bh_s, boff, off_s, MH);
    scatter_both_k<<<NBE, 256, 0, stream>>>(src, dst, off_d, off_s, pairs, sbyte);
    bucket_csr_ocnt_k<<<2 * NBUK, 512, 0, stream>>>(pairs, off_d, sbyte, off_s,
                                                    rowptr, col, inorm, onorm);

    // ---- weight fusion (independent of CSR chain)
    w12_k<<<65, 256, 0, stream>>>(W1, W2, b1, b2, W12, b12);

    const int ntiles = NN / 16;          // 6250 (exact)
    const int ggrid  = 512;
    const int fgrid  = 2048;             // fused: 8.4KB LDS, high residency

    // h16a = (x @ W12 + b12) * onorm          (fused feature1+feature2)
    mfma_gemm_k<8, false, false, true, true><<<ggrid, 256, 0, stream>>>(
        x, nullptr, W12, b12, h16a, onorm, NN, 128, ntiles);

    // layer 0: gather(h16a) -> conv -> h16b   (fp16, *onorm)
    agg_conv_k<false><<<fgrid, 256, 0, stream>>>(
        (const float4*)h16a, rowptr, col, inorm, onorm,
        Wg, bg, h16b, ntiles);
    // layer 1: gather(h16b) -> conv -> h16a
    agg_conv_k<false><<<fgrid, 256, 0, stream>>>(
        (const float4*)h16b, rowptr, col, inorm, onorm,
        Wg + 128 * 128, bg + 128, h16a, ntiles);
    // layer 2: gather(h16a) -> conv -> h1     (fp32, no onorm)
    agg_conv_k<true><<<fgrid, 256, 0, stream>>>(
        (const float4*)h16a, rowptr, col, inorm, onorm,
        Wg + 2 * 128 * 128, bg + 256, h1, ntiles);

    // out = h1 @ Wc + bc
    mfma_gemm_k<3, false, false, false, false><<<ggrid, 256, 0, stream>>>(
        h1, nullptr, Wc, bc, out, nullptr, NN, 40, ntiles);
}

// Round 7
// 559.245 us; speedup vs baseline: 1.0895x; 1.0895x over previous
//
#include <hip/hip_runtime.h>
#include <hip/hip_fp16.h>
#include <cstdint>
#include <cstddef>

constexpr int NN  = 100000;
constexpr int EE  = 1600000;
constexpr int HID = 128;
constexpr int BUK = 256;                      // nodes per bucket (local id fits 8 bits)
constexpr int NBUK = (NN + BUK - 1) / BUK;    // 391 buckets
constexpr int BLKE = 2048;                    // edges per block in bucket passes
constexpr int NBE  = (EE + BLKE - 1) / BLKE;  // 782 edge blocks
constexpr int MH   = NBUK * NBE;              // 305762 flattened hist entries
constexpr int MH2  = 2 * MH;                  // concatenated dst|src histograms
constexpr int NSC  = (MH2 + 2047) / 2048;     // 299 scan chunks (<=512 for scan_top)

typedef float f32x4_t __attribute__((ext_vector_type(4)));
typedef short bf16x8_t __attribute__((ext_vector_type(8)));

static __device__ __forceinline__ short f2bf(float f) {
    union { float f; unsigned u; } x; x.f = f;
    unsigned r = x.u + 0x7FFF + ((x.u >> 16) & 1);   // RN-even
    return (short)(r >> 16);
}
static __device__ __forceinline__ float bf2f(short b) {
    union { unsigned u; float f; } x; x.u = ((unsigned)(unsigned short)b) << 16;
    return x.f;
}

// ---------------------------------------------------------------- pass 1: per-block bucket histograms, both sides (LDS atomics only)
// dst half -> bh2[0..MH), src half -> bh2[MH..2MH)
__global__ __launch_bounds__(256) void bh_both_k(const int* __restrict__ src, const int* __restrict__ dst,
                                                 int* __restrict__ bh2) {
    __shared__ int hd[NBUK], hs[NBUK];
    int blk = blockIdx.x, t = threadIdx.x;
    for (int i = t; i < NBUK; i += 256) { hd[i] = 0; hs[i] = 0; }
    __syncthreads();
    int e0 = blk * BLKE, e1 = min(e0 + BLKE, EE);
    for (int e = e0 + t; e < e1; e += 256) {
        atomicAdd(&hd[dst[e] >> 8], 1);
        atomicAdd(&hs[src[e] >> 8], 1);
    }
    __syncthreads();
    for (int i = t; i < NBUK; i += 256) {
        bh2[i * NBE + blk]      = hd[i];
        bh2[MH + i * NBE + blk] = hs[i];
    }
}

// ---------------------------------------------------------------- 3-level exclusive scan over 2*MH (2048 elems/block)
__global__ __launch_bounds__(256) void scan_sum_k(const int* __restrict__ in, int* __restrict__ bsum, int n) {
    __shared__ int sc[256];
    int b = blockIdx.x, t = threadIdx.x;
    int base = b * 2048 + t * 8;
    int s = 0;
#pragma unroll
    for (int j = 0; j < 8; j++) { int idx = base + j; s += (idx < n) ? in[idx] : 0; }
    sc[t] = s; __syncthreads();
    for (int off = 128; off > 0; off >>= 1) {
        if (t < off) sc[t] += sc[t + off];
        __syncthreads();
    }
    if (t == 0) bsum[b] = sc[0];
}

__global__ __launch_bounds__(512) void scan_top_k(const int* __restrict__ bsum, int* __restrict__ boff, int nb) {
    __shared__ int sc[512];
    int t = threadIdx.x;
    int v = (t < nb) ? bsum[t] : 0;
    sc[t] = v; __syncthreads();
    for (int off = 1; off < 512; off <<= 1) {
        int u = (t >= off) ? sc[t - off] : 0;
        __syncthreads();
        sc[t] += u;
        __syncthreads();
    }
    if (t < nb) boff[t] = sc[t] - v;
}

__global__ __launch_bounds__(256) void scan_chunk_k(const int* __restrict__ in, const int* __restrict__ boff,
                                                    int* __restrict__ out, int n) {
    __shared__ int sc[256];
    int b = blockIdx.x, t = threadIdx.x;
    int base = b * 2048 + t * 8;
    int c[8];
    int s = 0;
#pragma unroll
    for (int j = 0; j < 8; j++) { int idx = base + j; c[j] = (idx < n) ? in[idx] : 0; s += c[j]; }
    sc[t] = s; __syncthreads();
    for (int off = 1; off < 256; off <<= 1) {
        int v = (t >= off) ? sc[t - off] : 0;
        __syncthreads();
        sc[t] += v;
        __syncthreads();
    }
    int excl = sc[t] - s + boff[b];
#pragma unroll
    for (int j = 0; j < 8; j++) {
        int idx = base + j;
        if (idx < n) out[idx] = excl;
        excl += c[j];
    }
}

// ---------------------------------------------------------------- pass 2: scatter into bucket order (LDS cursors)
// dst side: packed 25-bit payload (d_local<<17 | src); src side: low byte only
// src-half offsets carry +EE (concatenated scan) -> subtract at cursor load
__global__ __launch_bounds__(256) void scatter_both_k(const int* __restrict__ src, const int* __restrict__ dst,
                                                      const int* __restrict__ off2,
                                                      unsigned* __restrict__ pairs, unsigned char* __restrict__ sbyte) {
    __shared__ int cd[NBUK], cs[NBUK];
    int blk = blockIdx.x, t = threadIdx.x;
    for (int i = t; i < NBUK; i += 256) {
        cd[i] = off2[i * NBE + blk];
        cs[i] = off2[MH + i * NBE + blk] - EE;
    }
    __syncthreads();
    int e0 = blk * BLKE, e1 = min(e0 + BLKE, EE);
    for (int e = e0 + t; e < e1; e += 256) {
        int d = dst[e], s = src[e];
        int pd = atomicAdd(&cd[d >> 8], 1);
        pairs[pd] = ((unsigned)(d & 255) << 17) | (unsigned)s;
        int ps = atomicAdd(&cs[s >> 8], 1);
        sbyte[ps] = (unsigned char)(s & 255);
    }
}

// ---------------------------------------------------------------- per-bucket work, fused:
// blocks [0, NBUK):     in-deg hist -> inorm, rowptr, col  (from pairs)
// blocks [NBUK, 2*NBUK): out-deg hist -> onorm             (from sbyte)
__global__ __launch_bounds__(512) void bucket_csr_ocnt_k(
    const unsigned* __restrict__ pairs, const unsigned char* __restrict__ sbyte,
    const int* __restrict__ off2,
    int* __restrict__ rowptr, int* __restrict__ col,
    float* __restrict__ inorm, float* __restrict__ onorm) {
    __shared__ int hist[BUK];
    __shared__ int excl[BUK];
    __shared__ int psum[BUK];
    int t = threadIdx.x;

    if (blockIdx.x >= NBUK) {            // -------- out-degree counting
        int b = blockIdx.x - NBUK;
        int base = off2[MH + b * NBE] - EE;
        int endv = (b == NBUK - 1) ? EE : off2[MH + (b + 1) * NBE] - EE;
        if (t < BUK) hist[t] = 0;
        __syncthreads();
        for (int i = base + t; i < endv; i += 512) atomicAdd(&hist[sbyte[i]], 1);
        __syncthreads();
        if (t < BUK) {
            int node = b * BUK + t;
            if (node < NN) {
                int c = hist[t]; if (c < 1) c = 1;
                onorm[node] = rsqrtf((float)c);
            }
        }
        return;
    }

    // ------------------------------------------- CSR build
    int b = blockIdx.x;
    int base = off2[b * NBE];
    int endv = (b == NBUK - 1) ? EE : off2[(b + 1) * NBE];
    if (t < BUK) hist[t] = 0;
    __syncthreads();
    for (int i = base + t; i < endv; i += 512) atomicAdd(&hist[pairs[i] >> 17], 1);
    __syncthreads();
    int ps = 0;
    if (t < BUK) { ps = hist[t]; psum[t] = ps; }
    __syncthreads();
    for (int off = 1; off < BUK; off <<= 1) {
        int u = 0;
        if (t < BUK && t >= off) u = psum[t - off];
        __syncthreads();
        if (t < BUK) psum[t] += u;
        __syncthreads();
    }
    if (t < BUK) {
        int pex = psum[t] - ps;
        excl[t] = pex;
        int node = b * BUK + t;
        if (node < NN) {
            rowptr[node] = base + pex;
            int c = ps; if (c < 1) c = 1;
            inorm[node] = rsqrtf((float)c);
        }
    }
    if (b == NBUK - 1 && t == 0) rowptr[NN] = EE;
    __syncthreads();
    for (int i = base + t; i < endv; i += 512) {
        unsigned p = pairs[i];
        int pos = base + atomicAdd(&excl[p >> 17], 1);
        col[pos] = (int)(p & 0x1FFFFu);
    }
}

// ---------------------------------------------------------------- W12 = W1 @ W2 ; b12 = b1 @ W2 + b2 (merged)
__global__ __launch_bounds__(256) void w12_k(const float* __restrict__ W1, const float* __restrict__ W2,
                                             const float* __restrict__ b1, const float* __restrict__ b2,
                                             float* __restrict__ W12, float* __restrict__ b12) {
    if (blockIdx.x == 64) {
        int j = threadIdx.x;
        if (j < 128) {
            float acc = b2[j];
            for (int k = 0; k < 128; k++) acc = fmaf(b1[k], W2[k * 128 + j], acc);
            b12[j] = acc;
        }
        return;
    }
    int idx = blockIdx.x * 256 + threadIdx.x;   // 0..16383
    int i = idx >> 7, j = idx & 127;
    float a0 = 0.f, a1 = 0.f, a2 = 0.f, a3 = 0.f;
    for (int k = 0; k < 128; k += 4) {
        a0 = fmaf(W1[i * 128 + k],     W2[(k)     * 128 + j], a0);
        a1 = fmaf(W1[i * 128 + k + 1], W2[(k + 1) * 128 + j], a1);
        a2 = fmaf(W1[i * 128 + k + 2], W2[(k + 2) * 128 + j], a2);
        a3 = fmaf(W1[i * 128 + k + 3], W2[(k + 3) * 128 + j], a3);
    }
    W12[idx] = (a0 + a1) + (a2 + a3);
}

// ---------------------------------------------------------------- aggregation (fp16 gather, fp32 acc, fp32 out)
// One wave per dst node; quarter-wave (16 lanes x 16B = one 256B fp16 row),
// 4 edges in flight per quarter in main loop, 2 in tail (R7). Output is
// PRE-SCALED by inorm (so downstream GEMM drops INSCALE). h16 is pre-scaled
// by onorm. No nontemporal hints (R3).
__global__ __launch_bounds__(256) void agg_k(const float4* __restrict__ h16, const int* __restrict__ rowptr,
                                             const int* __restrict__ col, const float* __restrict__ inorm,
                                             float4* __restrict__ out) {
    int w = (int)((blockIdx.x * 256 + threadIdx.x) >> 6);
    if (w >= NN) return;
    int lane = threadIdx.x & 63;
    int q   = lane >> 4;
    int l16 = lane & 15;
    int beg = rowptr[w], end = rowptr[w + 1];
    float acc[8];
#pragma unroll
    for (int j = 0; j < 8; j++) acc[j] = 0.f;

    union HU { float4 f4; __half2 h2[4]; };
    int i = beg + q;
    for (; i + 12 < end; i += 16) {        // per quarter: edges i, i+4, i+8, i+12
        int s0 = col[i], s1 = col[i + 4], s2 = col[i + 8], s3 = col[i + 12];
        HU u0, u1, u2, u3;
        u0.f4 = h16[(size_t)s0 * 16 + l16];
        u1.f4 = h16[(size_t)s1 * 16 + l16];
        u2.f4 = h16[(size_t)s2 * 16 + l16];
        u3.f4 = h16[(size_t)s3 * 16 + l16];
#pragma unroll
        for (int p = 0; p < 4; p++) {
            float2 a = __half22float2(u0.h2[p]);
            float2 b = __half22float2(u1.h2[p]);
            float2 c = __half22float2(u2.h2[p]);
            float2 d = __half22float2(u3.h2[p]);
            acc[2 * p]     += (a.x + b.x) + (c.x + d.x);
            acc[2 * p + 1] += (a.y + b.y) + (c.y + d.y);
        }
    }
    for (; i + 4 < end; i += 8) {          // tail: 2 edges in flight
        int s0 = col[i], s1 = col[i + 4];
        HU u0, u1;
        u0.f4 = h16[(size_t)s0 * 16 + l16];
        u1.f4 = h16[(size_t)s1 * 16 + l16];
#pragma unroll
        for (int p = 0; p < 4; p++) {
            float2 a = __half22float2(u0.h2[p]);
            float2 b = __half22float2(u1.h2[p]);
            acc[2 * p]     += a.x + b.x;
            acc[2 * p + 1] += a.y + b.y;
        }
    }
    if (i < end) {
        HU u; u.f4 = h16[(size_t)col[i] * 16 + l16];
#pragma unroll
        for (int p = 0; p < 4; p++) {
            float2 a = __half22float2(u.h2[p]);
            acc[2 * p]     += a.x;
            acc[2 * p + 1] += a.y;
        }
    }
#pragma unroll
    for (int mm = 16; mm <= 32; mm <<= 1)
#pragma unroll
        for (int j = 0; j < 8; j++) acc[j] += __shfl_xor(acc[j], mm);
    if (q == 0) {
        float s = inorm[w];
        float4 o0, o1;
        o0.x = acc[0] * s; o0.y = acc[1] * s; o0.z = acc[2] * s; o0.w = acc[3] * s;
        o1.x = acc[4] * s; o1.y = acc[5] * s; o1.z = acc[6] * s; o1.w = acc[7] * s;
        out[(size_t)w * 32 + l16 * 2]     = o0;
        out[(size_t)w * 32 + l16 * 2 + 1] = o1;
    }
}

// ---------------------------------------------------------------- split-bf16 MFMA GEMM, operand-swapped epilogue (R5-proven)
template <int NT, bool RELU, bool INSCALE, bool OUTSCALE, bool OUTHALF>
__global__ __launch_bounds__(256) void mfma_gemm_k(
    const float* __restrict__ in, const float* __restrict__ inscale,
    const float* __restrict__ W, const float* __restrict__ bias,
    void* __restrict__ outp, const float* __restrict__ outscale,
    int nrows, int ncols, int ntiles) {

    __shared__ short Bh[NT * 2048];   // [ntc][kblk(4)][lane(64)][j(8)]
    __shared__ short Bl[NT * 2048];

    const int t = threadIdx.x;

    if constexpr (NT == 8) {
        for (int j = 0; j < 16; j++) {
            int fi = (j * 256 + t) * 4;
            int k = fi >> 7, n0 = fi & 127;
            float4 wv = *(const float4*)(W + fi);
            float wa[4] = {wv.x, wv.y, wv.z, wv.w};
#pragma unroll
            for (int cc = 0; cc < 4; cc++) {
                int g = n0 + cc;
                int q2 = g >> 2;
                int ntc = q2 & 7;                       // % NT (NT=8)
                int c = ((q2 >> 3) << 2) | (g & 3);     // (q2/NT)*4 + (g&3)
                int kblk = k >> 5, ksub = k & 31;
                int lane_ = ((ksub >> 3) << 4) | c;
                int sidx = ((ntc * 4 + kblk) * 64 + lane_) * 8 + (ksub & 7);
                short hi = f2bf(wa[cc]);
                Bh[sidx] = hi; Bl[sidx] = f2bf(wa[cc] - bf2f(hi));
            }
        }
    } else {  // classifier: 40 real cols, pad to NT*16=48
        for (int idx = t; idx < 128 * 64; idx += 256) {
            int k = idx >> 6, g = idx & 63;
            if (g < NT * 16) {
                float w = (g < 40) ? W[k * 40 + g] : 0.f;
                int q2 = g >> 2;
                int ntc = q2 % NT;
                int c = (q2 / NT) * 4 + (g & 3);
                int kblk = k >> 5, ksub = k & 31;
                int lane_ = ((ksub >> 3) << 4) | c;
                int sidx = ((ntc * 4 + kblk) * 64 + lane_) * 8 + (ksub & 7);
                short hi = f2bf(w);
                Bh[sidx] = hi; Bl[sidx] = f2bf(w - bf2f(hi));
            }
        }
    }
    __syncthreads();   // LDS read-only below

    const int wave = t >> 6;
    const int lane = t & 63;
    const int m    = lane & 15;     // node within tile
    const int kq   = lane >> 4;
    const int cbase = kq * 4 * NT;  // this thread's first output col

    float bstat[4 * NT];
#pragma unroll
    for (int i = 0; i < 4 * NT; i++) {
        int g = cbase + i;
        bstat[i] = (g < ncols) ? bias[g] : 0.f;
    }

    const int wstride = gridDim.x * 4;
    for (int tile = blockIdx.x * 4 + wave; tile < ntiles; tile += wstride) {
        int row = tile * 16 + m;
        bool rv = row < nrows;

        bf16x8_t Ah[4], Al[4];
        float s = 1.f;
        if (INSCALE && rv) s = inscale[row];
#pragma unroll
        for (int kb = 0; kb < 4; kb++) {
            const float* ap = in + (size_t)row * 128 + kb * 32 + kq * 8;
            float4 p0, p1;
            if (rv) { p0 = *(const float4*)ap; p1 = *(const float4*)(ap + 4); }
            else    { p0 = make_float4(0,0,0,0); p1 = make_float4(0,0,0,0); }
            float av[8] = {p0.x, p0.y, p0.z, p0.w, p1.x, p1.y, p1.z, p1.w};
#pragma unroll
            for (int j = 0; j < 8; j++) {
                float v = INSCALE ? av[j] * s : av[j];
                short hi = f2bf(v);
                Ah[kb][j] = hi;
                Al[kb][j] = f2bf(v - bf2f(hi));
            }
        }

        float osc = 1.f;
        if (OUTSCALE && rv) osc = outscale[row];

        float ov[4 * NT] __attribute__((aligned(16)));
#pragma unroll
        for (int nt = 0; nt < NT; nt++) {
            f32x4_t acc = {0.f, 0.f, 0.f, 0.f};
#pragma unroll
            for (int kb = 0; kb < 4; kb++) {
                const bf16x8_t bh = *(const bf16x8_t*)&Bh[((nt * 4 + kb) * 64 + lane) * 8];
                const bf16x8_t bl = *(const bf16x8_t*)&Bl[((nt * 4 + kb) * 64 + lane) * 8];
                acc = __builtin_amdgcn_mfma_f32_16x16x32_bf16(bh, Ah[kb], acc, 0, 0, 0);
                acc = __builtin_amdgcn_mfma_f32_16x16x32_bf16(bh, Al[kb], acc, 0, 0, 0);
                acc = __builtin_amdgcn_mfma_f32_16x16x32_bf16(bl, Ah[kb], acc, 0, 0, 0);
            }
#pragma unroll
            for (int r = 0; r < 4; r++) {
                float v = acc[r] + bstat[nt * 4 + r];
                if (RELU) v = fmaxf(v, 0.f);
                ov[nt * 4 + r] = v * osc;
            }
        }

        if (rv) {
            if constexpr (OUTHALF) {
                union { __half h[4 * NT]; float4 f4[NT]; } U;
#pragma unroll
                for (int i = 0; i < 4 * NT; i++) U.h[i] = __float2half_rn(ov[i]);
                float4* p = (float4*)((__half*)outp + (size_t)row * ncols + cbase);
#pragma unroll
                for (int j = 0; j < NT; j += 2) p[j >> 1] = U.f4[j >> 1];   // NT=8: 4x16B
            } else if constexpr (NT == 8) {
                float4* p = (float4*)((float*)outp + (size_t)row * 128 + cbase);
#pragma unroll
                for (int j = 0; j < 8; j++) p[j] = ((const float4*)ov)[j];  // 8x16B
            } else {  // classifier fp32, ncols=40: cols cbase..cbase+11, skip >=40
                float* p = (float*)outp + (size_t)row * 40 + cbase;
#pragma unroll
                for (int j = 0; j < 3; j++) {
                    if (cbase + j * 4 < 40) *(float4*)(p + j * 4) = ((const float4*)ov)[j];
                }
            }
        }
    }
}

// ---------------------------------------------------------------- launch
extern "C" void kernel_launch(void* const* d_in, const int* in_sizes, int n_in,
                              void* d_out, int out_size, void* d_ws, size_t ws_size,
                              hipStream_t stream) {
    const float* x   = (const float*)d_in[0];
    const int*   src = (const int*)d_in[1];
    const int*   dst = (const int*)d_in[2];
    const float* W1  = (const float*)d_in[3];
    const float* b1  = (const float*)d_in[4];
    const float* W2  = (const float*)d_in[5];
    const float* b2  = (const float*)d_in[6];
    const float* Wg  = (const float*)d_in[7];   // [3][128][128]
    const float* bg  = (const float*)d_in[8];   // [3][128]
    const float* Wc  = (const float*)d_in[9];   // [128][40]
    const float* bc  = (const float*)d_in[10];  // [40]
    float* out = (float*)d_out;

    char* ws = (char*)d_ws;
    size_t off = 0;
    auto alloc = [&](size_t bytes) -> void* {
        void* p = ws + off;
        off += (bytes + 255) & ~(size_t)255;
        return p;
    };
    float*  h0     = (float*)alloc((size_t)NN * HID * 4);    // agg out (fp32, inorm-scaled)
    float*  h1     = (float*)alloc((size_t)NN * HID * 4);    // conv2 out (fp32)
    __half* h16    = (__half*)alloc((size_t)NN * HID * 2);   // agg in (fp16)
    float*  W12    = (float*)alloc(128 * 128 * 4);
    float*  b12    = (float*)alloc(128 * 4);
    float*  onorm  = (float*)alloc((size_t)NN * 4);
    float*  inorm  = (float*)alloc((size_t)NN * 4);
    int*    rowptr = (int*)alloc((size_t)(NN + 1) * 4);
    int*    col    = (int*)alloc((size_t)EE * 4);
    int*    bh2    = (int*)alloc((size_t)MH2 * 4);
    int*    off2   = (int*)alloc((size_t)MH2 * 4);
    int*    bsum   = (int*)alloc((size_t)NSC * 4);
    int*    boff   = (int*)alloc((size_t)NSC * 4);
    // sort payloads alias h0 (consumed by bucket_csr_ocnt_k before agg writes h0)
    unsigned*      pairs = (unsigned*)h0;                          // 6.4 MB
    unsigned char* sbyte = (unsigned char*)h0 + (size_t)EE * 4;    // 1.6 MB

    // ---- CSR build (no global atomics): single merged scan over dst|src
    bh_both_k<<<NBE, 256, 0, stream>>>(src, dst, bh2);
    scan_sum_k<<<NSC, 256, 0, stream>>>(bh2, bsum, MH2);
    scan_top_k<<<1, 512, 0, stream>>>(bsum, boff, NSC);
    scan_chunk_k<<<NSC, 256, 0, stream>>>(bh2, boff, off2, MH2);
    scatter_both_k<<<NBE, 256, 0, stream>>>(src, dst, off2, pairs, sbyte);
    bucket_csr_ocnt_k<<<2 * NBUK, 512, 0, stream>>>(pairs, sbyte, off2,
                                                    rowptr, col, inorm, onorm);

    // ---- weight fusion (independent of CSR chain)
    w12_k<<<65, 256, 0, stream>>>(W1, W2, b1, b2, W12, b12);

    const int ntiles = NN / 16;          // 6250 (exact)
    const int ggrid  = 512;

    // h16 = (x @ W12 + b12) * onorm           (fused feature1+feature2)
    mfma_gemm_k<8, false, false, true, true><<<ggrid, 256, 0, stream>>>(
        x, nullptr, W12, b12, h16, onorm, NN, 128, ntiles);
    for (int l = 0; l < 3; l++) {
        // h0 = inorm * sum_{src} h16[src]     (pre-scaled in agg)
        agg_k<<<(NN * 64 + 255) / 256, 256, 0, stream>>>(
            (const float4*)h16, rowptr, col, inorm, (float4*)h0);
        if (l < 2) {
            // h16 = relu(h0 @ Wg + bg) * onorm   (fp16 out, feeds agg)
            mfma_gemm_k<8, true, false, true, true><<<ggrid, 256, 0, stream>>>(
                h0, nullptr, Wg + (size_t)l * 128 * 128, bg + (size_t)l * 128, h16, onorm, NN, 128, ntiles);
        } else {
            // h1 = relu(h0 @ Wg + bg)            (fp32, feeds classifier)
            mfma_gemm_k<8, true, false, false, false><<<ggrid, 256, 0, stream>>>(
                h0, nullptr, Wg + (size_t)l * 128 * 128, bg + (size_t)l * 128, h1, nullptr, NN, 128, ntiles);
        }
    }
    // out = h1 @ Wc + bc
    mfma_gemm_k<3, false, false, false, false><<<ggrid, 256, 0, stream>>>(
        h1, nullptr, Wc, bc, out, nullptr, NN, 40, ntiles);
}

// Round 8
// 556.197 us; speedup vs baseline: 1.0954x; 1.0055x over previous
//
#include <hip/hip_runtime.h>
#include <hip/hip_fp16.h>
#include <cstdint>
#include <cstddef>

constexpr int NN  = 100000;
constexpr int EE  = 1600000;
constexpr int HID = 128;
constexpr int BUK = 256;                      // nodes per bucket (local id fits 8 bits)
constexpr int NBUK = (NN + BUK - 1) / BUK;    // 391 buckets
constexpr int BLKE = 2048;                    // edges per block in bucket passes
constexpr int NBE  = (EE + BLKE - 1) / BLKE;  // 782 edge blocks
constexpr int MH   = NBUK * NBE;              // 305762 flattened hist entries
constexpr int MH2  = 2 * MH;                  // concatenated dst|src histograms
constexpr int NSC  = (MH2 + 2047) / 2048;     // 299 scan chunks (<=512 for scan_top)

typedef float f32x4_t __attribute__((ext_vector_type(4)));
typedef short bf16x8_t __attribute__((ext_vector_type(8)));

static __device__ __forceinline__ short f2bf(float f) {
    union { float f; unsigned u; } x; x.f = f;
    unsigned r = x.u + 0x7FFF + ((x.u >> 16) & 1);   // RN-even
    return (short)(r >> 16);
}
static __device__ __forceinline__ float bf2f(short b) {
    union { unsigned u; float f; } x; x.u = ((unsigned)(unsigned short)b) << 16;
    return x.f;
}

// ---------------------------------------------------------------- pass 1: per-block bucket histograms, both sides (LDS atomics only)
// dst half -> bh2[0..MH), src half -> bh2[MH..2MH)
__global__ __launch_bounds__(256) void bh_both_k(const int* __restrict__ src, const int* __restrict__ dst,
                                                 int* __restrict__ bh2) {
    __shared__ int hd[NBUK], hs[NBUK];
    int blk = blockIdx.x, t = threadIdx.x;
    for (int i = t; i < NBUK; i += 256) { hd[i] = 0; hs[i] = 0; }
    __syncthreads();
    int e0 = blk * BLKE, e1 = min(e0 + BLKE, EE);
    for (int e = e0 + t; e < e1; e += 256) {
        atomicAdd(&hd[dst[e] >> 8], 1);
        atomicAdd(&hs[src[e] >> 8], 1);
    }
    __syncthreads();
    for (int i = t; i < NBUK; i += 256) {
        bh2[i * NBE + blk]      = hd[i];
        bh2[MH + i * NBE + blk] = hs[i];
    }
}

// ---------------------------------------------------------------- 3-level exclusive scan over 2*MH (2048 elems/block)
__global__ __launch_bounds__(256) void scan_sum_k(const int* __restrict__ in, int* __restrict__ bsum, int n) {
    __shared__ int sc[256];
    int b = blockIdx.x, t = threadIdx.x;
    int base = b * 2048 + t * 8;
    int s = 0;
#pragma unroll
    for (int j = 0; j < 8; j++) { int idx = base + j; s += (idx < n) ? in[idx] : 0; }
    sc[t] = s; __syncthreads();
    for (int off = 128; off > 0; off >>= 1) {
        if (t < off) sc[t] += sc[t + off];
        __syncthreads();
    }
    if (t == 0) bsum[b] = sc[0];
}

__global__ __launch_bounds__(512) void scan_top_k(const int* __restrict__ bsum, int* __restrict__ boff, int nb) {
    __shared__ int sc[512];
    int t = threadIdx.x;
    int v = (t < nb) ? bsum[t] : 0;
    sc[t] = v; __syncthreads();
    for (int off = 1; off < 512; off <<= 1) {
        int u = (t >= off) ? sc[t - off] : 0;
        __syncthreads();
        sc[t] += u;
        __syncthreads();
    }
    if (t < nb) boff[t] = sc[t] - v;
}

__global__ __launch_bounds__(256) void scan_chunk_k(const int* __restrict__ in, const int* __restrict__ boff,
                                                    int* __restrict__ out, int n) {
    __shared__ int sc[256];
    int b = blockIdx.x, t = threadIdx.x;
    int base = b * 2048 + t * 8;
    int c[8];
    int s = 0;
#pragma unroll
    for (int j = 0; j < 8; j++) { int idx = base + j; c[j] = (idx < n) ? in[idx] : 0; s += c[j]; }
    sc[t] = s; __syncthreads();
    for (int off = 1; off < 256; off <<= 1) {
        int v = (t >= off) ? sc[t - off] : 0;
        __syncthreads();
        sc[t] += v;
        __syncthreads();
    }
    int excl = sc[t] - s + boff[b];
#pragma unroll
    for (int j = 0; j < 8; j++) {
        int idx = base + j;
        if (idx < n) out[idx] = excl;
        excl += c[j];
    }
}

// ---------------------------------------------------------------- pass 2: scatter into bucket order (LDS cursors)
// dst side: packed 25-bit payload (d_local<<17 | src); src side: low byte only
// src-half offsets carry +EE (concatenated scan) -> subtract at cursor load
__global__ __launch_bounds__(256) void scatter_both_k(const int* __restrict__ src, const int* __restrict__ dst,
                                                      const int* __restrict__ off2,
                                                      unsigned* __restrict__ pairs, unsigned char* __restrict__ sbyte) {
    __shared__ int cd[NBUK], cs[NBUK];
    int blk = blockIdx.x, t = threadIdx.x;
    for (int i = t; i < NBUK; i += 256) {
        cd[i] = off2[i * NBE + blk];
        cs[i] = off2[MH + i * NBE + blk] - EE;
    }
    __syncthreads();
    int e0 = blk * BLKE, e1 = min(e0 + BLKE, EE);
    for (int e = e0 + t; e < e1; e += 256) {
        int d = dst[e], s = src[e];
        int pd = atomicAdd(&cd[d >> 8], 1);
        pairs[pd] = ((unsigned)(d & 255) << 17) | (unsigned)s;
        int ps = atomicAdd(&cs[s >> 8], 1);
        sbyte[ps] = (unsigned char)(s & 255);
    }
}

// ---------------------------------------------------------------- per-bucket work, fused:
// blocks [0, NBUK):     in-deg hist -> inorm, rowptr, col  (from pairs)
// blocks [NBUK, 2*NBUK): out-deg hist -> onorm             (from sbyte)
__global__ __launch_bounds__(512) void bucket_csr_ocnt_k(
    const unsigned* __restrict__ pairs, const unsigned char* __restrict__ sbyte,
    const int* __restrict__ off2,
    int* __restrict__ rowptr, int* __restrict__ col,
    float* __restrict__ inorm, float* __restrict__ onorm) {
    __shared__ int hist[BUK];
    __shared__ int excl[BUK];
    __shared__ int psum[BUK];
    int t = threadIdx.x;

    if (blockIdx.x >= NBUK) {            // -------- out-degree counting
        int b = blockIdx.x - NBUK;
        int base = off2[MH + b * NBE] - EE;
        int endv = (b == NBUK - 1) ? EE : off2[MH + (b + 1) * NBE] - EE;
        if (t < BUK) hist[t] = 0;
        __syncthreads();
        for (int i = base + t; i < endv; i += 512) atomicAdd(&hist[sbyte[i]], 1);
        __syncthreads();
        if (t < BUK) {
            int node = b * BUK + t;
            if (node < NN) {
                int c = hist[t]; if (c < 1) c = 1;
                onorm[node] = rsqrtf((float)c);
            }
        }
        return;
    }

    // ------------------------------------------- CSR build
    int b = blockIdx.x;
    int base = off2[b * NBE];
    int endv = (b == NBUK - 1) ? EE : off2[(b + 1) * NBE];
    if (t < BUK) hist[t] = 0;
    __syncthreads();
    for (int i = base + t; i < endv; i += 512) atomicAdd(&hist[pairs[i] >> 17], 1);
    __syncthreads();
    int ps = 0;
    if (t < BUK) { ps = hist[t]; psum[t] = ps; }
    __syncthreads();
    for (int off = 1; off < BUK; off <<= 1) {
        int u = 0;
        if (t < BUK && t >= off) u = psum[t - off];
        __syncthreads();
        if (t < BUK) psum[t] += u;
        __syncthreads();
    }
    if (t < BUK) {
        int pex = psum[t] - ps;
        excl[t] = pex;
        int node = b * BUK + t;
        if (node < NN) {
            rowptr[node] = base + pex;
            int c = ps; if (c < 1) c = 1;
            inorm[node] = rsqrtf((float)c);
        }
    }
    if (b == NBUK - 1 && t == 0) rowptr[NN] = EE;
    __syncthreads();
    for (int i = base + t; i < endv; i += 512) {
        unsigned p = pairs[i];
        int pos = base + atomicAdd(&excl[p >> 17], 1);
        col[pos] = (int)(p & 0x1FFFFu);
    }
}

// ---------------------------------------------------------------- W12 = W1 @ W2 ; b12 = b1 @ W2 + b2 (merged)
__global__ __launch_bounds__(256) void w12_k(const float* __restrict__ W1, const float* __restrict__ W2,
                                             const float* __restrict__ b1, const float* __restrict__ b2,
                                             float* __restrict__ W12, float* __restrict__ b12) {
    if (blockIdx.x == 64) {
        int j = threadIdx.x;
        if (j < 128) {
            float acc = b2[j];
            for (int k = 0; k < 128; k++) acc = fmaf(b1[k], W2[k * 128 + j], acc);
            b12[j] = acc;
        }
        return;
    }
    int idx = blockIdx.x * 256 + threadIdx.x;   // 0..16383
    int i = idx >> 7, j = idx & 127;
    float a0 = 0.f, a1 = 0.f, a2 = 0.f, a3 = 0.f;
    for (int k = 0; k < 128; k += 4) {
        a0 = fmaf(W1[i * 128 + k],     W2[(k)     * 128 + j], a0);
        a1 = fmaf(W1[i * 128 + k + 1], W2[(k + 1) * 128 + j], a1);
        a2 = fmaf(W1[i * 128 + k + 2], W2[(k + 2) * 128 + j], a2);
        a3 = fmaf(W1[i * 128 + k + 3], W2[(k + 3) * 128 + j], a3);
    }
    W12[idx] = (a0 + a1) + (a2 + a3);
}

// ---------------------------------------------------------------- aggregation (fp16 gather, fp32 acc, split-bf16 out)
// R0-proven gather: one wave per dst node; quarter-wave (16 lanes x 16B =
// one 256B fp16 row), 4 edges in flight per quarter, 1-edge tail (R5 form —
// R7's 2-edge tail was +1us/+1.7MB). h16 is pre-scaled by onorm.
// R8: epilogue scales by inorm and emits the SPLIT-BF16 planes (hi, lo)
// directly — same f2bf formula the GEMM used, bit-identical fragments —
// moving ~256 VALU ops/tile/thread out of the conv GEMMs into agg's idle
// latency slots (VALUBusy was 40%).
__global__ __launch_bounds__(256) void agg_k(const float4* __restrict__ h16, const int* __restrict__ rowptr,
                                             const int* __restrict__ col, const float* __restrict__ inorm,
                                             short* __restrict__ h0h, short* __restrict__ h0l) {
    int w = (int)((blockIdx.x * 256 + threadIdx.x) >> 6);
    if (w >= NN) return;
    int lane = threadIdx.x & 63;
    int q   = lane >> 4;
    int l16 = lane & 15;
    int beg = rowptr[w], end = rowptr[w + 1];
    float acc[8];
#pragma unroll
    for (int j = 0; j < 8; j++) acc[j] = 0.f;

    union HU { float4 f4; __half2 h2[4]; };
    int i = beg + q;
    for (; i + 12 < end; i += 16) {        // per quarter: edges i, i+4, i+8, i+12
        int s0 = col[i], s1 = col[i + 4], s2 = col[i + 8], s3 = col[i + 12];
        HU u0, u1, u2, u3;
        u0.f4 = h16[(size_t)s0 * 16 + l16];
        u1.f4 = h16[(size_t)s1 * 16 + l16];
        u2.f4 = h16[(size_t)s2 * 16 + l16];
        u3.f4 = h16[(size_t)s3 * 16 + l16];
#pragma unroll
        for (int p = 0; p < 4; p++) {
            float2 a = __half22float2(u0.h2[p]);
            float2 b = __half22float2(u1.h2[p]);
            float2 c = __half22float2(u2.h2[p]);
            float2 d = __half22float2(u3.h2[p]);
            acc[2 * p]     += (a.x + b.x) + (c.x + d.x);
            acc[2 * p + 1] += (a.y + b.y) + (c.y + d.y);
        }
    }
    for (; i < end; i += 4) {
        int s = col[i];
        HU u; u.f4 = h16[(size_t)s * 16 + l16];
#pragma unroll
        for (int p = 0; p < 4; p++) {
            float2 a = __half22float2(u.h2[p]);
            acc[2 * p]     += a.x;
            acc[2 * p + 1] += a.y;
        }
    }
#pragma unroll
    for (int mm = 16; mm <= 32; mm <<= 1)
#pragma unroll
        for (int j = 0; j < 8; j++) acc[j] += __shfl_xor(acc[j], mm);
    if (q == 0) {
        float s = inorm[w];
        bf16x8_t hv, lv;
#pragma unroll
        for (int j = 0; j < 8; j++) {
            float v = acc[j] * s;
            short hi = f2bf(v);
            hv[j] = hi;
            lv[j] = f2bf(v - bf2f(hi));
        }
        *(bf16x8_t*)&h0h[(size_t)w * 128 + l16 * 8] = hv;
        *(bf16x8_t*)&h0l[(size_t)w * 128 + l16 * 8] = lv;
    }
}

// ---------------------------------------------------------------- split-bf16 MFMA GEMM, operand-swapped epilogue (R5-proven)
// INSPLIT (R8): A-fragments pre-split by agg_k -> direct bf16x8 loads from
// the two planes, no conversion ALU on the load->MFMA path.
template <int NT, bool RELU, bool OUTSCALE, bool OUTHALF, bool INSPLIT>
__global__ __launch_bounds__(256) void mfma_gemm_k(
    const void* __restrict__ in, const short* __restrict__ inl,
    const float* __restrict__ W, const float* __restrict__ bias,
    void* __restrict__ outp, const float* __restrict__ outscale,
    int nrows, int ncols, int ntiles) {

    __shared__ short Bh[NT * 2048];   // [ntc][kblk(4)][lane(64)][j(8)]
    __shared__ short Bl[NT * 2048];

    const int t = threadIdx.x;

    if constexpr (NT == 8) {
        for (int j = 0; j < 16; j++) {
            int fi = (j * 256 + t) * 4;
            int k = fi >> 7, n0 = fi & 127;
            float4 wv = *(const float4*)(W + fi);
            float wa[4] = {wv.x, wv.y, wv.z, wv.w};
#pragma unroll
            for (int cc = 0; cc < 4; cc++) {
                int g = n0 + cc;
                int q2 = g >> 2;
                int ntc = q2 & 7;                       // % NT (NT=8)
                int c = ((q2 >> 3) << 2) | (g & 3);     // (q2/NT)*4 + (g&3)
                int kblk = k >> 5, ksub = k & 31;
                int lane_ = ((ksub >> 3) << 4) | c;
                int sidx = ((ntc * 4 + kblk) * 64 + lane_) * 8 + (ksub & 7);
                short hi = f2bf(wa[cc]);
                Bh[sidx] = hi; Bl[sidx] = f2bf(wa[cc] - bf2f(hi));
            }
        }
    } else {  // classifier: 40 real cols, pad to NT*16=48
        for (int idx = t; idx < 128 * 64; idx += 256) {
            int k = idx >> 6, g = idx & 63;
            if (g < NT * 16) {
                float w = (g < 40) ? ((const float*)W)[k * 40 + g] : 0.f;
                int q2 = g >> 2;
                int ntc = q2 % NT;
                int c = (q2 / NT) * 4 + (g & 3);
                int kblk = k >> 5, ksub = k & 31;
                int lane_ = ((ksub >> 3) << 4) | c;
                int sidx = ((ntc * 4 + kblk) * 64 + lane_) * 8 + (ksub & 7);
                short hi = f2bf(w);
                Bh[sidx] = hi; Bl[sidx] = f2bf(w - bf2f(hi));
            }
        }
    }
    __syncthreads();   // LDS read-only below

    const int wave = t >> 6;
    const int lane = t & 63;
    const int m    = lane & 15;     // node within tile
    const int kq   = lane >> 4;
    const int cbase = kq * 4 * NT;  // this thread's first output col

    float bstat[4 * NT];
#pragma unroll
    for (int i = 0; i < 4 * NT; i++) {
        int g = cbase + i;
        bstat[i] = (g < ncols) ? bias[g] : 0.f;
    }

    const int wstride = gridDim.x * 4;
    for (int tile = blockIdx.x * 4 + wave; tile < ntiles; tile += wstride) {
        int row = tile * 16 + m;
        bool rv = row < nrows;

        bf16x8_t Ah[4], Al[4];
        if constexpr (INSPLIT) {
            const short* ih = (const short*)in + (size_t)row * 128 + kq * 8;
            const short* il = inl + (size_t)row * 128 + kq * 8;
#pragma unroll
            for (int kb = 0; kb < 4; kb++) {
                if (rv) {
                    Ah[kb] = *(const bf16x8_t*)(ih + kb * 32);
                    Al[kb] = *(const bf16x8_t*)(il + kb * 32);
                } else {
                    Ah[kb] = (bf16x8_t){0,0,0,0,0,0,0,0};
                    Al[kb] = (bf16x8_t){0,0,0,0,0,0,0,0};
                }
            }
        } else {
#pragma unroll
            for (int kb = 0; kb < 4; kb++) {
                const float* ap = (const float*)in + (size_t)row * 128 + kb * 32 + kq * 8;
                float4 p0, p1;
                if (rv) { p0 = *(const float4*)ap; p1 = *(const float4*)(ap + 4); }
                else    { p0 = make_float4(0,0,0,0); p1 = make_float4(0,0,0,0); }
                float av[8] = {p0.x, p0.y, p0.z, p0.w, p1.x, p1.y, p1.z, p1.w};
#pragma unroll
                for (int j = 0; j < 8; j++) {
                    float v = av[j];
                    short hi = f2bf(v);
                    Ah[kb][j] = hi;
                    Al[kb][j] = f2bf(v - bf2f(hi));
                }
            }
        }

        float osc = 1.f;
        if (OUTSCALE && rv) osc = outscale[row];

        float ov[4 * NT] __attribute__((aligned(16)));
#pragma unroll
        for (int nt = 0; nt < NT; nt++) {
            f32x4_t acc = {0.f, 0.f, 0.f, 0.f};
#pragma unroll
            for (int kb = 0; kb < 4; kb++) {
                const bf16x8_t bh = *(const bf16x8_t*)&Bh[((nt * 4 + kb) * 64 + lane) * 8];
                const bf16x8_t bl = *(const bf16x8_t*)&Bl[((nt * 4 + kb) * 64 + lane) * 8];
                acc = __builtin_amdgcn_mfma_f32_16x16x32_bf16(bh, Ah[kb], acc, 0, 0, 0);
                acc = __builtin_amdgcn_mfma_f32_16x16x32_bf16(bh, Al[kb], acc, 0, 0, 0);
                acc = __builtin_amdgcn_mfma_f32_16x16x32_bf16(bl, Ah[kb], acc, 0, 0, 0);
            }
#pragma unroll
            for (int r = 0; r < 4; r++) {
                float v = acc[r] + bstat[nt * 4 + r];
                if (RELU) v = fmaxf(v, 0.f);
                ov[nt * 4 + r] = v * osc;
            }
        }

        if (rv) {
            if constexpr (OUTHALF) {
                union { __half h[4 * NT]; float4 f4[NT]; } U;
#pragma unroll
                for (int i = 0; i < 4 * NT; i++) U.h[i] = __float2half_rn(ov[i]);
                float4* p = (float4*)((__half*)outp + (size_t)row * ncols + cbase);
#pragma unroll
                for (int j = 0; j < NT; j += 2) p[j >> 1] = U.f4[j >> 1];   // NT=8: 4x16B
            } else if constexpr (NT == 8) {
                float4* p = (float4*)((float*)outp + (size_t)row * 128 + cbase);
#pragma unroll
                for (int j = 0; j < 8; j++) p[j] = ((const float4*)ov)[j];  // 8x16B
            } else {  // classifier fp32, ncols=40: cols cbase..cbase+11, skip >=40
                float* p = (float*)outp + (size_t)row * 40 + cbase;
#pragma unroll
                for (int j = 0; j < 3; j++) {
                    if (cbase + j * 4 < 40) *(float4*)(p + j * 4) = ((const float4*)ov)[j];
                }
            }
        }
    }
}

// ---------------------------------------------------------------- launch
extern "C" void kernel_launch(void* const* d_in, const int* in_sizes, int n_in,
                              void* d_out, int out_size, void* d_ws, size_t ws_size,
                              hipStream_t stream) {
    const float* x   = (const float*)d_in[0];
    const int*   src = (const int*)d_in[1];
    const int*   dst = (const int*)d_in[2];
    const float* W1  = (const float*)d_in[3];
    const float* b1  = (const float*)d_in[4];
    const float* W2  = (const float*)d_in[5];
    const float* b2  = (const float*)d_in[6];
    const float* Wg  = (const float*)d_in[7];   // [3][128][128]
    const float* bg  = (const float*)d_in[8];   // [3][128]
    const float* Wc  = (const float*)d_in[9];   // [128][40]
    const float* bc  = (const float*)d_in[10];  // [40]
    float* out = (float*)d_out;

    char* ws = (char*)d_ws;
    size_t off = 0;
    auto alloc = [&](size_t bytes) -> void* {
        void* p = ws + off;
        off += (bytes + 255) & ~(size_t)255;
        return p;
    };
    short*  h0h    = (short*)alloc((size_t)NN * HID * 2);    // agg out hi plane (bf16)
    short*  h0l    = (short*)alloc((size_t)NN * HID * 2);    // agg out lo plane (bf16)
    float*  h1     = (float*)alloc((size_t)NN * HID * 4);    // conv2 out (fp32)
    __half* h16    = (__half*)alloc((size_t)NN * HID * 2);   // agg in (fp16)
    float*  W12    = (float*)alloc(128 * 128 * 4);
    float*  b12    = (float*)alloc(128 * 4);
    float*  onorm  = (float*)alloc((size_t)NN * 4);
    float*  inorm  = (float*)alloc((size_t)NN * 4);
    int*    rowptr = (int*)alloc((size_t)(NN + 1) * 4);
    int*    col    = (int*)alloc((size_t)EE * 4);
    int*    bh2    = (int*)alloc((size_t)MH2 * 4);
    int*    off2   = (int*)alloc((size_t)MH2 * 4);
    int*    bsum   = (int*)alloc((size_t)NSC * 4);
    int*    boff   = (int*)alloc((size_t)NSC * 4);
    // sort payloads alias h0h/h0l (consumed by bucket_csr_ocnt_k before agg writes)
    unsigned*      pairs = (unsigned*)h0h;                          // 6.4 MB
    unsigned char* sbyte = (unsigned char*)h0h + (size_t)EE * 4;    // 1.6 MB (within h0h's 25.6MB)

    // ---- CSR build (no global atomics): single merged scan over dst|src
    bh_both_k<<<NBE, 256, 0, stream>>>(src, dst, bh2);
    scan_sum_k<<<NSC, 256, 0, stream>>>(bh2, bsum, MH2);
    scan_top_k<<<1, 512, 0, stream>>>(bsum, boff, NSC);
    scan_chunk_k<<<NSC, 256, 0, stream>>>(bh2, boff, off2, MH2);
    scatter_both_k<<<NBE, 256, 0, stream>>>(src, dst, off2, pairs, sbyte);
    bucket_csr_ocnt_k<<<2 * NBUK, 512, 0, stream>>>(pairs, sbyte, off2,
                                                    rowptr, col, inorm, onorm);

    // ---- weight fusion (independent of CSR chain)
    w12_k<<<65, 256, 0, stream>>>(W1, W2, b1, b2, W12, b12);

    const int ntiles = NN / 16;          // 6250 (exact)
    const int ggrid  = 512;

    // h16 = (x @ W12 + b12) * onorm           (fused feature1+feature2)
    mfma_gemm_k<8, false, true, true, false><<<ggrid, 256, 0, stream>>>(
        x, nullptr, W12, b12, h16, onorm, NN, 128, ntiles);
    for (int l = 0; l < 3; l++) {
        // (h0h,h0l) = split( inorm * sum_{src} h16[src] )
        agg_k<<<(NN * 64 + 255) / 256, 256, 0, stream>>>(
            (const float4*)h16, rowptr, col, inorm, h0h, h0l);
        if (l < 2) {
            // h16 = relu(h0 @ Wg + bg) * onorm   (fp16 out, feeds agg)
            mfma_gemm_k<8, true, true, true, true><<<ggrid, 256, 0, stream>>>(
                h0h, h0l, Wg + (size_t)l * 128 * 128, bg + (size_t)l * 128, h16, onorm, NN, 128, ntiles);
        } else {
            // h1 = relu(h0 @ Wg + bg)            (fp32, feeds classifier)
            mfma_gemm_k<8, true, false, false, true><<<ggrid, 256, 0, stream>>>(
                h0h, h0l, Wg + (size_t)l * 128 * 128, bg + (size_t)l * 128, h1, nullptr, NN, 128, ntiles);
        }
    }
    // out = h1 @ Wc + bc
    mfma_gemm_k<3, false, false, false, false><<<ggrid, 256, 0, stream>>>(
        h1, nullptr, Wc, bc, out, nullptr, NN, 40, ntiles);
}